// Round 20
// baseline (143.680 us; speedup 1.0000x reference)
//
#include <hip/hip_runtime.h>
#include <hip/hip_bf16.h>

#define N_NODES 100000
#define N_EDGES 1600000
#define IN_F 256
#define OUT_F 128

#define NBUCK 782          // ceil(100000 / 128), 128 rows per parent bucket
#define CH 2048            // edges per scatter block (fits 32 KB LDS)
#define NSCAT ((N_EDGES + CH - 1) / CH)  // 782
#define NGEMMR ((N_NODES + 127) / 128)   // 782 row-blocks; x2 col-halves = 1564
#define HCAP 2048          // srt capacity per half-bucket (mean 1023, max ~1200)
#define BCAP 3072          // fixed ebuf slab per bucket (mean 2046, max ~2250)

typedef __attribute__((ext_vector_type(8))) short bhalf8;
typedef __attribute__((ext_vector_type(4))) float f32x4;

static __device__ __forceinline__ unsigned short f2bfs(float f) {
    __hip_bfloat16 h = __float2bfloat16(f);
    return *reinterpret_cast<unsigned short*>(&h);
}

// ---------------- W^T pre-pass: Wt[col][k] = bf16(W[k][col]) ----------------
__global__ __launch_bounds__(256) void wt_kernel(
    const float* __restrict__ W, unsigned short* __restrict__ Wt)
{
    const int idx = blockIdx.x * 256 + threadIdx.x;
    const int col = idx >> 8;
    const int k   = idx & 255;
    Wt[idx] = f2bfs(W[(size_t)k * OUT_F + col]);
}

// ---------------- fused: scatter blocks (first NSCAT) + gemm blocks ----------
// Both branches fit 32 KB LDS -> 4 blocks/CU = 32 waves/CU.
// scatter LDS: buf 16K | bb 4K | h 3136 | cur 3136 | gbase 3136 | ps 2K = 31.9K
// gemm LDS: 64 cols x 256 k x 2B = 32K (column-half of W^T)
__global__ __launch_bounds__(512) void fused_kernel(
    const float* __restrict__ x, const unsigned short* __restrict__ Wt,
    unsigned short* __restrict__ support,
    const int* __restrict__ erow, const int* __restrict__ ecol,
    const float* __restrict__ eval, int* __restrict__ bcnt,
    int2* __restrict__ ebuf)
{
    __shared__ __align__(16) char smem[32768];
    const int tid = threadIdx.x;

    if (blockIdx.x < NSCAT) {
        // ---------------- bucket scatter into fixed per-bucket slabs ----------
        int2*           buf   = (int2*)smem;                       // 16 KB
        unsigned short* bb    = (unsigned short*)(smem + 16384);   // 4 KB
        int*            h     = (int*)(smem + 20480);              // 3136 B
        int*            cur   = (int*)(smem + 23616);              // 3136 B
        int*            gbase = (int*)(smem + 26752);              // 3136 B
        int*            ps    = (int*)(smem + 29888);              // 2048 B

        const int e0 = blockIdx.x * CH;
        const int e1 = min(e0 + CH, N_EDGES);
        const int n  = e1 - e0;

        for (int i = tid; i < NBUCK; i += 512) h[i] = 0;
        __syncthreads();

        for (int e = e0 + tid; e < e1; e += 512)
            atomicAdd(&h[erow[e] >> 7], 1);
        __syncthreads();

        // scan h (2 bins per thread) -> exclusive local bases in cur
        {
            const int idx0 = tid * 2;
            int sum = 0;
            #pragma unroll
            for (int k = 0; k < 2; ++k) { const int ii = idx0 + k; if (ii < NBUCK) sum += h[ii]; }
            ps[tid] = sum;
            __syncthreads();
            for (int off = 1; off < 512; off <<= 1) {
                const int a  = (tid >= off) ? ps[tid - off] : 0;
                const int x0 = ps[tid];
                __syncthreads();
                ps[tid] = x0 + a;
                __syncthreads();
            }
            int run = (tid == 0) ? 0 : ps[tid - 1];
            #pragma unroll
            for (int k = 0; k < 2; ++k) {
                const int ii = idx0 + k;
                if (ii < NBUCK) { cur[ii] = run; run += h[ii]; }
            }
        }
        __syncthreads();

        for (int e = e0 + tid; e < e1; e += 512) {
            const int r = erow[e];
            const int b = r >> 7;
            const int p = atomicAdd(&cur[b], 1);
            buf[p] = make_int2(((r & 127) << 17) | ecol[e], __float_as_int(eval[e]));
            bb[p]  = (unsigned short)b;
        }
        __syncthreads();

        for (int i = tid; i < NBUCK; i += 512)
            gbase[i] = h[i] ? (i * BCAP + atomicAdd(&bcnt[i], h[i])) : 0;
        __syncthreads();

        for (int i = tid; i < n; i += 512) {
            const int b  = bb[i];
            const int lb = cur[b] - h[b];
            ebuf[gbase[b] + (i - lb)] = buf[i];
        }
    } else {
        // ------------- MFMA GEMM: 128 rows x 64-col half of support ----------
        unsigned short* Bs = (unsigned short*)smem;   // 32 KB: 64 cols x 256 k

        const int gb     = blockIdx.x - NSCAT;
        const int rowblk = gb >> 1;
        const int chalf  = gb & 1;            // which 64-col half

        // Stage half W^T: 8 threads per col-row (64 rows x 512 B), swizzled.
        {
            const int row  = tid >> 3;        // 0..63 (local col)
            const int part = tid & 7;
            const uint4* src = (const uint4*)(Wt + (size_t)(chalf * 64 + row) * 256);
            uint4* dst       = (uint4*)(Bs + (size_t)row * 256);
            const int sw = row & 7;
            #pragma unroll
            for (int i = part * 4; i < part * 4 + 4; ++i)
                dst[i ^ sw] = src[i];
        }
        __syncthreads();

        const int wave = tid >> 6, lane = tid & 63;
        const int r_lo = lane & 15;
        const int kq   = lane >> 4;
        const int row0 = rowblk * 128 + wave * 16;
        const int row  = row0 + r_lo;        // this lane's output row

        const float* xa = x + (size_t)min(row, N_NODES - 1) * IN_F + kq * 8;

        f32x4 acc[4];
        #pragma unroll
        for (int c = 0; c < 4; ++c) acc[c] = (f32x4)0.f;

        #pragma unroll
        for (int ks = 0; ks < 8; ++ks) {
            const float4 al = *(const float4*)(xa + ks * 32);
            const float4 ah = *(const float4*)(xa + ks * 32 + 4);

            bhalf8 A;
            A[0] = (short)f2bfs(al.x); A[1] = (short)f2bfs(al.y);
            A[2] = (short)f2bfs(al.z); A[3] = (short)f2bfs(al.w);
            A[4] = (short)f2bfs(ah.x); A[5] = (short)f2bfs(ah.y);
            A[6] = (short)f2bfs(ah.z); A[7] = (short)f2bfs(ah.w);

            #pragma unroll
            for (int cf = 0; cf < 4; ++cf) {
                const int lcol = cf * 16 + r_lo;      // local Bs row
                const int off  = ((ks * 32 + kq * 8) ^ ((lcol & 7) << 3));
                const bhalf8 B = *(const bhalf8*)(Bs + (size_t)lcol * 256 + off);
                acc[cf] = __builtin_amdgcn_mfma_f32_16x16x32_bf16(B, A, acc[cf], 0, 0, 0);
            }
        }

        if (row < N_NODES) {
            unsigned short* dst = support + (size_t)row * OUT_F + chalf * 64 + kq * 4;
            #pragma unroll
            for (int cf = 0; cf < 4; ++cf) {
                ushort4 s4;
                s4.x = f2bfs(acc[cf][0]);
                s4.y = f2bfs(acc[cf][1]);
                s4.z = f2bfs(acc[cf][2]);
                s4.w = f2bfs(acc[cf][3]);
                *(ushort4*)(dst + cf * 16) = s4;
            }
        }
    }
}

// ---------------- hspmm: half-bucket per block; in-LDS hist + place + reduce ----
// XCD-paired mapping: the two halves of a parent bucket are 8 dispatch slots
// apart -> same XCD (blockIdx % 8), concurrent -> slab reads hit L2.
__global__ __launch_bounds__(256) void hspmm_kernel(
    const int* __restrict__ bcnt, const int2* __restrict__ ebuf,
    const unsigned short* __restrict__ support,
    const float* __restrict__ bias, float* __restrict__ out)
{
    __shared__ int2 srt[HCAP];   // 16 KB
    __shared__ int rc[64];
    __shared__ int rb[65];
    __shared__ int cc[64];

    const int id = blockIdx.x;
    const int q8 = id >> 4, r16 = id & 15;
    const int pb = (q8 << 3) | (r16 & 7);      // parent 128-row bucket
    const unsigned hf = (unsigned)(r16 >> 3);  // which 64-row half
    if (pb >= NBUCK) return;                   // grid padded to 1568
    const int row0 = (pb << 7) + ((int)hf << 6);
    if (row0 >= N_NODES) return;               // uniform across block
    const int nrows = min(64, N_NODES - row0);

    const int tid  = threadIdx.x;
    const int lane = tid & 63;
    const int grp  = tid >> 4;            // 16 groups per block
    const int l4   = tid & 15;            // 16B chunk within the 256B row

    const int beg = pb * BCAP;
    const int end = beg + bcnt[pb];

    if (tid < 64) rc[tid] = 0;
    __syncthreads();

    // pass 1: histogram of this half's 64 rows
    for (int i = beg + tid; i < end; i += 256) {
        const unsigned ex = (unsigned)ebuf[i].x;
        const unsigned lr7 = (ex >> 17) & 127u;
        if ((lr7 >> 6) == hf) atomicAdd(&rc[lr7 & 63], 1);
    }
    __syncthreads();

    // one-wave inclusive scan of 64 bins
    if (tid < 64) {
        int v = rc[tid];
        #pragma unroll
        for (int off = 1; off < 64; off <<= 1) {
            const int t = __shfl_up(v, off);
            if (lane >= off) v += t;
        }
        rb[tid + 1] = v;
        cc[tid] = v - rc[tid];
        if (tid == 0) rb[0] = 0;
    }
    __syncthreads();

    // pass 2: place row-grouped into srt
    for (int i = beg + tid; i < end; i += 256) {
        const int2 e = ebuf[i];
        const unsigned lr7 = ((unsigned)e.x >> 17) & 127u;
        if ((lr7 >> 6) == hf)
            srt[atomicAdd(&cc[lr7 & 63], 1)] = e;
    }
    __syncthreads();

#define ACC(V, U)                                            \
    a0 += (V) * __uint_as_float((U).x << 16);                \
    a1 += (V) * __uint_as_float((U).x & 0xFFFF0000u);        \
    a2 += (V) * __uint_as_float((U).y << 16);                \
    a3 += (V) * __uint_as_float((U).y & 0xFFFF0000u);        \
    a4 += (V) * __uint_as_float((U).z << 16);                \
    a5 += (V) * __uint_as_float((U).z & 0xFFFF0000u);        \
    a6 += (V) * __uint_as_float((U).w << 16);                \
    a7 += (V) * __uint_as_float((U).w & 0xFFFF0000u);

    // reduce pass: group `grp` owns rows grp, grp+16, grp+32, grp+48
    const float4 bv0 = *(const float4*)(bias + l4 * 8);
    const float4 bv1 = *(const float4*)(bias + l4 * 8 + 4);

    for (int lr = grp; lr < nrows; lr += 16) {
        const int s  = rb[lr];
        const int t2 = rb[lr + 1];
        float a0 = 0.f, a1 = 0.f, a2 = 0.f, a3 = 0.f;
        float a4 = 0.f, a5 = 0.f, a6 = 0.f, a7 = 0.f;
        int j = s;
        for (; j + 4 <= t2; j += 4) {
            const int2 e0 = srt[j],     e1 = srt[j + 1];
            const int2 e2 = srt[j + 2], e3 = srt[j + 3];
            const uint4 u0 = *(const uint4*)(support + ((size_t)(e0.x & 0x1FFFF) << 7) + l4 * 8);
            const uint4 u1 = *(const uint4*)(support + ((size_t)(e1.x & 0x1FFFF) << 7) + l4 * 8);
            const uint4 u2 = *(const uint4*)(support + ((size_t)(e2.x & 0x1FFFF) << 7) + l4 * 8);
            const uint4 u3 = *(const uint4*)(support + ((size_t)(e3.x & 0x1FFFF) << 7) + l4 * 8);
            const float v0 = __int_as_float(e0.y), v1 = __int_as_float(e1.y);
            const float v2 = __int_as_float(e2.y), v3 = __int_as_float(e3.y);
            ACC(v0, u0) ACC(v1, u1) ACC(v2, u2) ACC(v3, u3)
        }
        for (; j < t2; ++j) {
            const int2 e = srt[j];
            const uint4 u = *(const uint4*)(support + ((size_t)(e.x & 0x1FFFF) << 7) + l4 * 8);
            const float v = __int_as_float(e.y);
            ACC(v, u)
        }
        float4* o = (float4*)(out + ((size_t)(row0 + lr) << 7) + l4 * 8);
        o[0] = make_float4(a0 + bv0.x, a1 + bv0.y, a2 + bv0.z, a3 + bv0.w);
        o[1] = make_float4(a4 + bv1.x, a5 + bv1.y, a6 + bv1.z, a7 + bv1.w);
    }
#undef ACC
}

extern "C" void kernel_launch(void* const* d_in, const int* in_sizes, int n_in,
                              void* d_out, int out_size, void* d_ws, size_t ws_size,
                              hipStream_t stream) {
    const float* x    = (const float*)d_in[0];
    const int*   erow = (const int*)  d_in[1];
    const int*   ecol = (const int*)  d_in[2];
    const float* eval = (const float*)d_in[3];
    const float* W    = (const float*)d_in[4];
    const float* bias = (const float*)d_in[5];
    float*       out  = (float*)d_out;

    // workspace layout (16B-aligned chunks)
    char* ws = (char*)d_ws;
    unsigned short* support = (unsigned short*)ws; ws += (size_t)N_NODES * OUT_F * 2;  // 25.6 MB
    unsigned short* Wt      = (unsigned short*)ws; ws += (size_t)OUT_F * IN_F * 2;     // 64 KB
    int*  bcnt  = (int*)ws;                        ws += 3136;
    int2* ebuf  = (int2*)ws;                       ws += (size_t)NBUCK * BCAP * 8;      // 19.2 MB

    hipMemsetAsync(bcnt, 0, NBUCK * 4, stream);

    wt_kernel<<<(OUT_F * IN_F) / 256, 256, 0, stream>>>(W, Wt);

    // fused: 782 scatter blocks (dispatched first) + 1564 gemm blocks
    fused_kernel<<<NSCAT + 2 * NGEMMR, 512, 0, stream>>>(
        x, Wt, support, erow, ecol, eval, bcnt, ebuf);

    // grid padded to 1568 (98 x 16) for the XCD-paired mapping
    hspmm_kernel<<<1568, 256, 0, stream>>>(bcnt, ebuf, support, bias, out);
}

// Round 21
// 117.720 us; speedup vs baseline: 1.2205x; 1.2205x over previous
//
#include <hip/hip_runtime.h>
#include <hip/hip_bf16.h>

#define N_NODES 100000
#define N_EDGES 1600000
#define IN_F 256
#define OUT_F 128

#define NBUCK 782          // ceil(100000 / 128), 128 rows per parent bucket
#define CH 4096            // edges per scatter block
#define NSCAT ((N_EDGES + CH - 1) / CH)  // 391
#define NGEMM ((N_NODES + 127) / 128)    // 782
#define HCAP 2048          // srt capacity per half-bucket (mean 1023, max ~1200)
#define BCAP 3072          // fixed ebuf slab per bucket (mean 2046, max ~2250)

typedef __attribute__((ext_vector_type(8))) short bhalf8;
typedef __attribute__((ext_vector_type(4))) float f32x4;

static __device__ __forceinline__ unsigned short f2bfs(float f) {
    __hip_bfloat16 h = __float2bfloat16(f);
    return *reinterpret_cast<unsigned short*>(&h);
}

// ---------------- W^T pre-pass (also zeroes bcnt): Wt[col][k] = bf16(W[k][col])
__global__ __launch_bounds__(256) void wt_kernel(
    const float* __restrict__ W, unsigned short* __restrict__ Wt,
    int* __restrict__ bcnt)
{
    const int idx = blockIdx.x * 256 + threadIdx.x;
    const int col = idx >> 8;
    const int k   = idx & 255;
    Wt[idx] = f2bfs(W[(size_t)k * OUT_F + col]);
    if (blockIdx.x == 0)
        for (int i = threadIdx.x; i < NBUCK; i += 256) bcnt[i] = 0;
}

// ---------------- fused: bscatter blocks (first NSCAT) + gemm blocks ----------
// Both bodies are block-uniform branches sharing one 64 KB LDS region.
__global__ __launch_bounds__(512) void fused_kernel(
    const float* __restrict__ x, const unsigned short* __restrict__ Wt,
    unsigned short* __restrict__ support,
    const int* __restrict__ erow, const int* __restrict__ ecol,
    const float* __restrict__ eval, int* __restrict__ bcnt,
    int2* __restrict__ ebuf)
{
    __shared__ __align__(16) char smem[65536];
    const int tid = threadIdx.x;

    if (blockIdx.x < NSCAT) {
        // ---------------- bucket scatter into fixed per-bucket slabs ----------
        int2*           buf   = (int2*)smem;                       // 32 KB
        unsigned short* bb    = (unsigned short*)(smem + 32768);   // 8 KB
        int*            h     = (int*)(smem + 40960);
        int*            cur   = (int*)(smem + 44096);
        int*            gbase = (int*)(smem + 47232);
        int*            ps    = (int*)(smem + 50368);              // 512 ints

        const int e0 = blockIdx.x * CH;
        const int e1 = min(e0 + CH, N_EDGES);
        const int n  = e1 - e0;

        for (int i = tid; i < NBUCK; i += 512) h[i] = 0;
        __syncthreads();

        for (int e = e0 + tid; e < e1; e += 512)
            atomicAdd(&h[erow[e] >> 7], 1);
        __syncthreads();

        // scan h (2 bins per thread) -> exclusive local bases in cur
        {
            const int idx0 = tid * 2;
            int sum = 0;
            #pragma unroll
            for (int k = 0; k < 2; ++k) { const int ii = idx0 + k; if (ii < NBUCK) sum += h[ii]; }
            ps[tid] = sum;
            __syncthreads();
            for (int off = 1; off < 512; off <<= 1) {
                const int a  = (tid >= off) ? ps[tid - off] : 0;
                const int x0 = ps[tid];
                __syncthreads();
                ps[tid] = x0 + a;
                __syncthreads();
            }
            int run = (tid == 0) ? 0 : ps[tid - 1];
            #pragma unroll
            for (int k = 0; k < 2; ++k) {
                const int ii = idx0 + k;
                if (ii < NBUCK) { cur[ii] = run; run += h[ii]; }
            }
        }
        __syncthreads();

        for (int e = e0 + tid; e < e1; e += 512) {
            const int r = erow[e];
            const int b = r >> 7;
            const int p = atomicAdd(&cur[b], 1);
            buf[p] = make_int2(((r & 127) << 17) | ecol[e], __float_as_int(eval[e]));
            bb[p]  = (unsigned short)b;
        }
        __syncthreads();

        for (int i = tid; i < NBUCK; i += 512)
            gbase[i] = h[i] ? (i * BCAP + atomicAdd(&bcnt[i], h[i])) : 0;
        __syncthreads();

        for (int i = tid; i < n; i += 512) {
            const int b  = bb[i];
            const int lb = cur[b] - h[b];
            ebuf[gbase[b] + (i - lb)] = buf[i];
        }
    } else {
        // ---------------- MFMA GEMM: support(bf16) = x @ W -------------------
        unsigned short* Bs = (unsigned short*)smem;   // 64 KB

        // Stage W^T: 4 threads per row (128 rows x 512 B), swizzled uint4 slots.
        {
            const int row = tid >> 2;        // 0..127
            const int q   = tid & 3;
            const uint4* src = (const uint4*)(Wt + (size_t)row * 256);
            uint4* dst       = (uint4*)(Bs + (size_t)row * 256);
            const int sw = row & 7;
            #pragma unroll
            for (int i = q * 8; i < q * 8 + 8; ++i)
                dst[i ^ sw] = src[i];
        }
        __syncthreads();

        const int wave = tid >> 6, lane = tid & 63;
        const int r_lo = lane & 15;
        const int kq   = lane >> 4;
        const int row0 = (blockIdx.x - NSCAT) * 128 + wave * 16;
        const int row  = row0 + r_lo;        // this lane's output row

        const float* xa = x + (size_t)min(row, N_NODES - 1) * IN_F + kq * 8;

        f32x4 acc[8];
        #pragma unroll
        for (int c = 0; c < 8; ++c) acc[c] = (f32x4)0.f;

        #pragma unroll
        for (int ks = 0; ks < 8; ++ks) {
            const float4 al = *(const float4*)(xa + ks * 32);
            const float4 ah = *(const float4*)(xa + ks * 32 + 4);

            bhalf8 A;
            A[0] = (short)f2bfs(al.x); A[1] = (short)f2bfs(al.y);
            A[2] = (short)f2bfs(al.z); A[3] = (short)f2bfs(al.w);
            A[4] = (short)f2bfs(ah.x); A[5] = (short)f2bfs(ah.y);
            A[6] = (short)f2bfs(ah.z); A[7] = (short)f2bfs(ah.w);

            #pragma unroll
            for (int cf = 0; cf < 8; ++cf) {
                const int col = cf * 16 + r_lo;
                const int off = ((ks * 32 + kq * 8) ^ ((col & 7) << 3));
                const bhalf8 B = *(const bhalf8*)(Bs + (size_t)col * 256 + off);
                acc[cf] = __builtin_amdgcn_mfma_f32_16x16x32_bf16(B, A, acc[cf], 0, 0, 0);
            }
        }

        if (row < N_NODES) {
            unsigned short* dst = support + (size_t)row * OUT_F + kq * 4;
            #pragma unroll
            for (int cf = 0; cf < 8; ++cf) {
                ushort4 s4;
                s4.x = f2bfs(acc[cf][0]);
                s4.y = f2bfs(acc[cf][1]);
                s4.z = f2bfs(acc[cf][2]);
                s4.w = f2bfs(acc[cf][3]);
                *(ushort4*)(dst + cf * 16) = s4;
            }
        }
    }
}

// ---------------- hspmm: half-bucket per block; in-LDS hist + place + reduce ----
// XCD-paired mapping: the two halves of a parent bucket are 8 dispatch slots
// apart -> same XCD (blockIdx % 8), concurrent -> slab reads hit L2.
__global__ __launch_bounds__(256) void hspmm_kernel(
    const int* __restrict__ bcnt, const int2* __restrict__ ebuf,
    const unsigned short* __restrict__ support,
    const float* __restrict__ bias, float* __restrict__ out)
{
    __shared__ int2 srt[HCAP];   // 16 KB
    __shared__ int rc[64];
    __shared__ int rb[65];
    __shared__ int cc[64];

    const int id = blockIdx.x;
    const int q8 = id >> 4, r16 = id & 15;
    const int pb = (q8 << 3) | (r16 & 7);      // parent 128-row bucket
    const unsigned hf = (unsigned)(r16 >> 3);  // which 64-row half
    if (pb >= NBUCK) return;                   // grid padded to 1568
    const int row0 = (pb << 7) + ((int)hf << 6);
    if (row0 >= N_NODES) return;               // uniform across block
    const int nrows = min(64, N_NODES - row0);

    const int tid  = threadIdx.x;
    const int lane = tid & 63;
    const int grp  = tid >> 4;            // 16 groups per block
    const int l4   = tid & 15;            // 16B chunk within the 256B row

    const int beg = pb * BCAP;
    const int end = beg + bcnt[pb];

    if (tid < 64) rc[tid] = 0;
    __syncthreads();

    // pass 1: histogram of this half's 64 rows
    for (int i = beg + tid; i < end; i += 256) {
        const unsigned ex = (unsigned)ebuf[i].x;
        const unsigned lr7 = (ex >> 17) & 127u;
        if ((lr7 >> 6) == hf) atomicAdd(&rc[lr7 & 63], 1);
    }
    __syncthreads();

    // one-wave inclusive scan of 64 bins
    if (tid < 64) {
        int v = rc[tid];
        #pragma unroll
        for (int off = 1; off < 64; off <<= 1) {
            const int t = __shfl_up(v, off);
            if (lane >= off) v += t;
        }
        rb[tid + 1] = v;
        cc[tid] = v - rc[tid];
        if (tid == 0) rb[0] = 0;
    }
    __syncthreads();

    // pass 2: place row-grouped into srt
    for (int i = beg + tid; i < end; i += 256) {
        const int2 e = ebuf[i];
        const unsigned lr7 = ((unsigned)e.x >> 17) & 127u;
        if ((lr7 >> 6) == hf)
            srt[atomicAdd(&cc[lr7 & 63], 1)] = e;
    }
    __syncthreads();

#define ACC(V, U)                                            \
    a0 += (V) * __uint_as_float((U).x << 16);                \
    a1 += (V) * __uint_as_float((U).x & 0xFFFF0000u);        \
    a2 += (V) * __uint_as_float((U).y << 16);                \
    a3 += (V) * __uint_as_float((U).y & 0xFFFF0000u);        \
    a4 += (V) * __uint_as_float((U).z << 16);                \
    a5 += (V) * __uint_as_float((U).z & 0xFFFF0000u);        \
    a6 += (V) * __uint_as_float((U).w << 16);                \
    a7 += (V) * __uint_as_float((U).w & 0xFFFF0000u);

    // reduce pass: group `grp` owns rows grp, grp+16, grp+32, grp+48
    const float4 bv0 = *(const float4*)(bias + l4 * 8);
    const float4 bv1 = *(const float4*)(bias + l4 * 8 + 4);

    for (int lr = grp; lr < nrows; lr += 16) {
        const int s  = rb[lr];
        const int t2 = rb[lr + 1];
        float a0 = 0.f, a1 = 0.f, a2 = 0.f, a3 = 0.f;
        float a4 = 0.f, a5 = 0.f, a6 = 0.f, a7 = 0.f;
        int j = s;
        for (; j + 4 <= t2; j += 4) {
            const int2 e0 = srt[j],     e1 = srt[j + 1];
            const int2 e2 = srt[j + 2], e3 = srt[j + 3];
            const uint4 u0 = *(const uint4*)(support + ((size_t)(e0.x & 0x1FFFF) << 7) + l4 * 8);
            const uint4 u1 = *(const uint4*)(support + ((size_t)(e1.x & 0x1FFFF) << 7) + l4 * 8);
            const uint4 u2 = *(const uint4*)(support + ((size_t)(e2.x & 0x1FFFF) << 7) + l4 * 8);
            const uint4 u3 = *(const uint4*)(support + ((size_t)(e3.x & 0x1FFFF) << 7) + l4 * 8);
            const float v0 = __int_as_float(e0.y), v1 = __int_as_float(e1.y);
            const float v2 = __int_as_float(e2.y), v3 = __int_as_float(e3.y);
            ACC(v0, u0) ACC(v1, u1) ACC(v2, u2) ACC(v3, u3)
        }
        for (; j < t2; ++j) {
            const int2 e = srt[j];
            const uint4 u = *(const uint4*)(support + ((size_t)(e.x & 0x1FFFF) << 7) + l4 * 8);
            const float v = __int_as_float(e.y);
            ACC(v, u)
        }
        float4* o = (float4*)(out + ((size_t)(row0 + lr) << 7) + l4 * 8);
        o[0] = make_float4(a0 + bv0.x, a1 + bv0.y, a2 + bv0.z, a3 + bv0.w);
        o[1] = make_float4(a4 + bv1.x, a5 + bv1.y, a6 + bv1.z, a7 + bv1.w);
    }
#undef ACC
}

extern "C" void kernel_launch(void* const* d_in, const int* in_sizes, int n_in,
                              void* d_out, int out_size, void* d_ws, size_t ws_size,
                              hipStream_t stream) {
    const float* x    = (const float*)d_in[0];
    const int*   erow = (const int*)  d_in[1];
    const int*   ecol = (const int*)  d_in[2];
    const float* eval = (const float*)d_in[3];
    const float* W    = (const float*)d_in[4];
    const float* bias = (const float*)d_in[5];
    float*       out  = (float*)d_out;

    // workspace layout (16B-aligned chunks)
    char* ws = (char*)d_ws;
    unsigned short* support = (unsigned short*)ws; ws += (size_t)N_NODES * OUT_F * 2;  // 25.6 MB
    unsigned short* Wt      = (unsigned short*)ws; ws += (size_t)OUT_F * IN_F * 2;     // 64 KB
    int*  bcnt  = (int*)ws;                        ws += 3136;
    int2* ebuf  = (int2*)ws;                       ws += (size_t)NBUCK * BCAP * 8;      // 19.2 MB

    // wt also zeroes bcnt (stream-ordered before fused)
    wt_kernel<<<(OUT_F * IN_F) / 256, 256, 0, stream>>>(W, Wt, bcnt);

    // fused: 391 scatter blocks (dispatched first) + 782 gemm blocks
    fused_kernel<<<NSCAT + NGEMM, 512, 0, stream>>>(
        x, Wt, support, erow, ecol, eval, bcnt, ebuf);

    // grid padded to 1568 (98 x 16) for the XCD-paired mapping
    hspmm_kernel<<<1568, 256, 0, stream>>>(bcnt, ebuf, support, bias, out);
}